// Round 1
// baseline (119.799 us; speedup 1.0000x reference)
//
#include <hip/hip_runtime.h>

#define K_SPARSE 64
#define COLS     4096
#define NTHREADS 256
#define EPT      (COLS / NTHREADS)   // 16 elements per thread
#define VPT      (EPT / 4)           // 4 float4 per thread
#define NREP     8                   // histogram replicas (contention fix)

// Order-preserving fp32 -> uint32 mapping (ascending float order == ascending uint order)
__device__ __forceinline__ unsigned mapf(unsigned b) {
    return (b & 0x80000000u) ? ~b : (b | 0x80000000u);
}
__device__ __forceinline__ float unmapf(unsigned u) {
    unsigned b = (u & 0x80000000u) ? (u ^ 0x80000000u) : ~u;
    return __uint_as_float(b);
}

__global__ __launch_bounds__(NTHREADS)
void ksparse_rowsel(const float* __restrict__ x, float* __restrict__ out, int rows)
{
    const int row = blockIdx.x;
    if (row >= rows) return;
    const int t = threadIdx.x;

    const float4* __restrict__ xrow =
        reinterpret_cast<const float4*>(x) + (size_t)row * (COLS / 4);
    float4* __restrict__ orow =
        reinterpret_cast<float4*>(out) + (size_t)row * (COLS / 4);

    // Load entire row into registers (coalesced float4), map to sortable uints.
    unsigned u[EPT];
#pragma unroll
    for (int i = 0; i < VPT; ++i) {
        float4 v = xrow[t + i * NTHREADS];
        u[i * 4 + 0] = mapf(__float_as_uint(v.x));
        u[i * 4 + 1] = mapf(__float_as_uint(v.y));
        u[i * 4 + 2] = mapf(__float_as_uint(v.z));
        u[i * 4 + 3] = mapf(__float_as_uint(v.w));
    }

    // Replicated histograms: hist[r][b] at word offset r*257+b -> bank (r+b)&31,
    // so the same bin in different replicas never shares a bank.
    __shared__ unsigned hist[NREP][257];
    __shared__ unsigned hsum[256];
    __shared__ unsigned s_prefix, s_target;
    if (t == 0) { s_prefix = 0u; s_target = K_SPARSE; }

    unsigned high_mask = 0u;
#pragma unroll
    for (int p = 0; p < 4; ++p) {
        const int shift = 24 - 8 * p;
#pragma unroll
        for (int r = 0; r < NREP; ++r) hist[r][t] = 0u;
        __syncthreads();

        const unsigned prefix = s_prefix;
        const unsigned target = s_target;   // descending 0-indexed rank within prefix class
        const int rep = t & (NREP - 1);
#pragma unroll
        for (int i = 0; i < EPT; ++i) {
            if ((u[i] & high_mask) == prefix)
                atomicAdd(&hist[rep][(u[i] >> shift) & 0xFFu], 1u);
        }
        __syncthreads();

        // Merge replicas: thread t owns bin t.
        unsigned tot = 0;
#pragma unroll
        for (int r = 0; r < NREP; ++r) tot += hist[r][t];
        hsum[t] = tot;
        __syncthreads();

        // Suffix sum: hsum[b] = # elements (matching prefix) with digit >= b.
        for (int off = 1; off < 256; off <<= 1) {
            unsigned v = hsum[t] + ((t + off < 256) ? hsum[t + off] : 0u);
            __syncthreads();
            hsum[t] = v;
            __syncthreads();
        }

        // Exactly one bin satisfies S[b+1] <= target < S[b].
        unsigned Sb  = hsum[t];
        unsigned Sb1 = (t < 255) ? hsum[t + 1] : 0u;
        if (Sb1 <= target && target < Sb) {
            s_prefix = prefix | ((unsigned)t << shift);
            s_target = target - Sb1;
        }
        high_mask |= (0xFFu << shift);
        __syncthreads();
    }

    // s_prefix is now the exact bit pattern of kth = sorted[n-1-K].
    const float kth = unmapf(s_prefix);

#pragma unroll
    for (int i = 0; i < VPT; ++i) {
        float4 o;
        float fx;
        fx = unmapf(u[i * 4 + 0]); o.x = (fx > kth) ? fx : 0.0f;
        fx = unmapf(u[i * 4 + 1]); o.y = (fx > kth) ? fx : 0.0f;
        fx = unmapf(u[i * 4 + 2]); o.z = (fx > kth) ? fx : 0.0f;
        fx = unmapf(u[i * 4 + 3]); o.w = (fx > kth) ? fx : 0.0f;
        orow[t + i * NTHREADS] = o;
    }
}

extern "C" void kernel_launch(void* const* d_in, const int* in_sizes, int n_in,
                              void* d_out, int out_size, void* d_ws, size_t ws_size,
                              hipStream_t stream) {
    const float* x = (const float*)d_in[0];
    float* out = (float*)d_out;
    const int rows = in_sizes[0] / COLS;
    ksparse_rowsel<<<rows, NTHREADS, 0, stream>>>(x, out, rows);
}

// Round 5
// 112.473 us; speedup vs baseline: 1.0651x; 1.0651x over previous
//
#include <hip/hip_runtime.h>

#define K_SPARSE 64
#define COLS     4096
#define NTHREADS 256
#define EPT      (COLS / NTHREADS)   // 16 elements per thread
#define VPT      (EPT / 4)           // 4 float4 per thread
#define NREP     8                   // histogram replicas (contention fix)

// Order-preserving fp32 -> uint32 mapping (ascending float order == ascending uint order)
__device__ __forceinline__ unsigned mapf(unsigned b) {
    return (b & 0x80000000u) ? ~b : (b | 0x80000000u);
}
__device__ __forceinline__ float unmapf(unsigned u) {
    unsigned b = (u & 0x80000000u) ? (u ^ 0x80000000u) : ~u;
    return __uint_as_float(b);
}

__global__ __launch_bounds__(NTHREADS)
void ksparse_rowsel(const float* __restrict__ x, float* __restrict__ out, int rows)
{
    const int row = blockIdx.x;
    if (row >= rows) return;
    const int t    = threadIdx.x;
    const int lane = t & 63;
    const int w    = t >> 6;          // wave id 0..3; wave w owns bins w*64..w*64+63

    const float4* __restrict__ xrow =
        reinterpret_cast<const float4*>(x) + (size_t)row * (COLS / 4);
    float4* __restrict__ orow =
        reinterpret_cast<float4*>(out) + (size_t)row * (COLS / 4);

    // Load entire row into registers (coalesced float4), map to sortable uints.
    unsigned u[EPT];
#pragma unroll
    for (int i = 0; i < VPT; ++i) {
        float4 v = xrow[t + i * NTHREADS];
        u[i * 4 + 0] = mapf(__float_as_uint(v.x));
        u[i * 4 + 1] = mapf(__float_as_uint(v.y));
        u[i * 4 + 2] = mapf(__float_as_uint(v.z));
        u[i * 4 + 3] = mapf(__float_as_uint(v.w));
    }

    // Replicated histograms: hist[r][b] at word offset r*257+b -> bank (r+b)&31,
    // so the same bin in different replicas never shares a bank.
    __shared__ unsigned hist[NREP][257];
    __shared__ unsigned wtot[4];
    __shared__ unsigned s_prefix, s_target;

    if (t == 0) { s_prefix = 0u; s_target = K_SPARSE; }
#pragma unroll
    for (int r = 0; r < NREP; ++r) hist[r][t] = 0u;
    __syncthreads();

    unsigned high_mask = 0u;
    const int rep = t & (NREP - 1);
#pragma unroll
    for (int p = 0; p < 4; ++p) {
        const int shift = 24 - 8 * p;
        const unsigned prefix = s_prefix;
        const unsigned target = s_target;   // descending 0-indexed rank within prefix class

#pragma unroll
        for (int i = 0; i < EPT; ++i) {
            if ((u[i] & high_mask) == prefix)
                atomicAdd(&hist[rep][(u[i] >> shift) & 0xFFu], 1u);
        }
        __syncthreads();                     // B1: all atomics for this pass done

        // Thread t owns bin t: merge replicas, then zero them (only this thread
        // ever reads bin t, so zeroing needs no barrier of its own).
        unsigned tot = 0;
#pragma unroll
        for (int r = 0; r < NREP; ++r) { tot += hist[r][t]; hist[r][t] = 0u; }

        // Wave-level inclusive SUFFIX scan over the wave's 64 bins (no barriers):
        // S_local[lane] = sum of tot over bins [lane..63] of this wave.
        unsigned s = tot;
#pragma unroll
        for (int off = 1; off < 64; off <<= 1) {
            unsigned v = __shfl_down(s, off, 64);
            if (lane + off < 64) s += v;
        }
        if (lane == 0) wtot[w] = s;          // wave total = suffix at lane 0
        // S[t+1] within the wave, before we need it (wave-synchronous shuffle):
        unsigned s_next = __shfl_down(s, 1, 64);
        __syncthreads();                     // B2: wtot visible

        // Cross-wave tail: sum of totals of later waves.
        unsigned later = 0;
#pragma unroll
        for (int ww = 0; ww < 4; ++ww) if (ww > w) later += wtot[ww];

        const unsigned Sb  = s + later;                          // S[t]
        const unsigned Sb1 = (lane < 63) ? (s_next + later) : later;  // S[t+1]
        if (Sb1 <= target && target < Sb) {   // exactly one thread in the block
            s_prefix = prefix | ((unsigned)t << shift);
            s_target = target - Sb1;
        }
        high_mask |= (0xFFu << shift);
        __syncthreads();                     // B3: selection (and zeroed hist) visible
    }

    // s_prefix is now the exact bit pattern of kth = sorted[n-1-K].
    const float kth = unmapf(s_prefix);

#pragma unroll
    for (int i = 0; i < VPT; ++i) {
        float4 o;
        float fx;
        fx = unmapf(u[i * 4 + 0]); o.x = (fx > kth) ? fx : 0.0f;
        fx = unmapf(u[i * 4 + 1]); o.y = (fx > kth) ? fx : 0.0f;
        fx = unmapf(u[i * 4 + 2]); o.z = (fx > kth) ? fx : 0.0f;
        fx = unmapf(u[i * 4 + 3]); o.w = (fx > kth) ? fx : 0.0f;
        orow[t + i * NTHREADS] = o;
    }
}

extern "C" void kernel_launch(void* const* d_in, const int* in_sizes, int n_in,
                              void* d_out, int out_size, void* d_ws, size_t ws_size,
                              hipStream_t stream) {
    const float* x = (const float*)d_in[0];
    float* out = (float*)d_out;
    const int rows = in_sizes[0] / COLS;
    ksparse_rowsel<<<rows, NTHREADS, 0, stream>>>(x, out, rows);
}